// Round 8
// baseline (62.702 us; speedup 1.0000x reference)
//
#include <hip/hip_runtime.h>

// Cascaded biquad IIR (DF2T) via linear state-space chunking. 3 kernels:
//   1) k_chunk_state: per-chunk final state from zero init
//   2) k_scan_par:    Kogge-Stone affine scan across chunks (wave 0 builds
//                     the A^L powers in-register via __shfl)
//   3) k_chunk_out:   replay each chunk from its exact initial state
// R8: 64-thread blocks owning 64 chunks (16 KiB LDS) -> 10 blocks/CU for
// block-level phase overlap; global_load_lds with pre-swizzled per-lane
// global source (linear LDS dest, swizzled read — both-sides rule).

namespace {
constexpr int NS     = 4;
constexpr int BATCH  = 512;
constexpr int TLEN   = 32768;      // 2^15
constexpr int NSTATE = 8;
constexpr int P      = 512;        // chunks per batch
constexpr int L      = TLEN / P;   // 64 steps
constexpr int LQ     = L / 4;      // 16 float4 per chunk
constexpr int LOG2P  = 9;
constexpr int LOG2L  = 6;
constexpr int NT     = 64;         // threads per chunk-kernel block
}

#if defined(__has_builtin)
#  if __has_builtin(__builtin_amdgcn_global_load_lds)
#    define USE_GLL 1
#  endif
#endif
#ifndef USE_GLL
#  define USE_GLL 0
#endif

__device__ __forceinline__ void load_coefs(const float* __restrict__ bc,
                                           const float* __restrict__ ac,
                                           float b0[NS], float b1[NS], float b2[NS],
                                           float a1[NS], float a2[NS]) {
#pragma unroll
  for (int k = 0; k < NS; ++k) {
    b0[k] = bc[3 * k];
    b1[k] = bc[3 * k + 1];
    b2[k] = bc[3 * k + 2];
    a1[k] = ac[2 * k];
    a2[k] = ac[2 * k + 1];
  }
}

// One time-step through the 4-section cascade (matches reference exactly).
__device__ __forceinline__ float step_cascade(float sig,
                                              const float b0[NS], const float b1[NS],
                                              const float b2[NS], const float a1[NS],
                                              const float a2[NS],
                                              float s1[NS], float s2[NS]) {
#pragma unroll
  for (int k = 0; k < NS; ++k) {
    float y = fmaf(b0[k], sig, s1[k]);
    s1[k]   = fmaf(-a1[k], y, fmaf(b1[k], sig, s2[k]));
    s2[k]   = fmaf(-a2[k], y, b2[k] * sig);
    sig = y;
  }
  return sig;
}

#define CO b0, b1, b2, a1, a2

__device__ __forceinline__ void adv4(const float4 u,
                                     const float b0[NS], const float b1[NS],
                                     const float b2[NS], const float a1[NS],
                                     const float a2[NS], float s1[NS], float s2[NS]) {
  (void)step_cascade(u.x, CO, s1, s2);
  (void)step_cascade(u.y, CO, s1, s2);
  (void)step_cascade(u.z, CO, s1, s2);
  (void)step_cascade(u.w, CO, s1, s2);
}

__device__ __forceinline__ float4 out4(const float4 u,
                                       const float b0[NS], const float b1[NS],
                                       const float b2[NS], const float a1[NS],
                                       const float a2[NS], float s1[NS], float s2[NS]) {
  float4 y;
  y.x = step_cascade(u.x, CO, s1, s2);
  y.y = step_cascade(u.y, CO, s1, s2);
  y.z = step_cascade(u.z, CO, s1, s2);
  y.w = step_cascade(u.w, CO, s1, s2);
  return y;
}

// LDS slot for (chunk c, float4 q): XOR swizzle; measured 0 bank conflicts (R7).
__device__ __forceinline__ int slot_of(int c, int q) {
  return c * LQ + (q ^ (c & (LQ - 1)));
}

// Stage this block's 16 KiB (64 chunks x 16 f4) into sbuf in swizzled layout.
// gsrc points at the block's first float4. t = threadIdx.x (64 threads).
__device__ __forceinline__ void stage_in(const float4* __restrict__ gsrc,
                                         float4* sbuf, int t) {
#if USE_GLL
#pragma unroll
  for (int k = 0; k < 16; ++k) {
    const int s = k * NT + t;          // linear LDS slot this lane fills
    const int c = s >> 4, q = s & 15;  // its (chunk, pos)
    // content for slot s = global f4 of chunk c at swizzled pos (both-sides rule)
    const float4* g = gsrc + c * LQ + (q ^ (c & 15));
    __builtin_amdgcn_global_load_lds(
        (const __attribute__((address_space(1))) void*)g,
        (__attribute__((address_space(3))) void*)&sbuf[k * NT], 16, 0, 0);
  }
#else
  float4 tmp[16];
#pragma unroll
  for (int k = 0; k < 16; ++k) {
    const int s = k * NT + t;
    const int c = s >> 4, q = s & 15;
    tmp[k] = gsrc[c * LQ + (q ^ (c & 15))];
  }
#pragma unroll
  for (int k = 0; k < 16; ++k) sbuf[k * NT + t] = tmp[k];
#endif
}

// ---------------------------------------------------------------------------
// Phase 1: block = 64 chunks (16 KiB). Stage in, one barrier, run each chunk
// from zero state, write final 8-float state.
__global__ __launch_bounds__(NT) void k_chunk_state(const float* __restrict__ x,
                                                    const float* __restrict__ bc,
                                                    const float* __restrict__ ac,
                                                    float* __restrict__ vbuf) {
  __shared__ float4 sbuf[NT * LQ];  // 16 KiB

  const int t = threadIdx.x;
  float b0[NS], b1[NS], b2[NS], a1[NS], a2[NS];
  load_coefs(bc, ac, b0, b1, b2, a1, a2);

  const float4* __restrict__ gsrc =
      reinterpret_cast<const float4*>(x) + (size_t)blockIdx.x * NT * LQ;

  stage_in(gsrc, sbuf, t);
  __syncthreads();

  float s1[NS] = {0.f, 0.f, 0.f, 0.f};
  float s2[NS] = {0.f, 0.f, 0.f, 0.f};
#pragma unroll
  for (int q = 0; q < LQ; ++q) adv4(sbuf[slot_of(t, q)], CO, s1, s2);

  float* __restrict__ vp = vbuf + ((size_t)blockIdx.x * NT + t) * NSTATE;
  *reinterpret_cast<float4*>(vp)     = make_float4(s1[0], s2[0], s1[1], s2[1]);
  *reinterpret_cast<float4*>(vp + 4) = make_float4(s1[2], s2[2], s1[3], s2[3]);
}

// ---------------------------------------------------------------------------
// Phase 2: Kogge-Stone affine scan. Wave 0 builds Ms[d] = (A^L)^(2^d)
// in-register via __shfl (14 squarings of the 8x8, one element per lane).
__global__ void k_scan_par(const float* __restrict__ bc,
                           const float* __restrict__ ac,
                           float* __restrict__ vbuf) {
  __shared__ float Ms[LOG2P][64];
  __shared__ float W[P][NSTATE + 1];  // stride 9: 2-way alias (free)

  const int t = threadIdx.x;  // P threads, block = one batch

  if (t < 64) {
    float b0[NS], b1[NS], b2[NS], a1[NS], a2[NS];
    load_coefs(bc, ac, b0, b1, b2, a1, a2);
    const int r = t >> 3, c = t & 7;
    float p1[NS] = {0.f, 0.f, 0.f, 0.f};
    float p2[NS] = {0.f, 0.f, 0.f, 0.f};
    if (c & 1) p2[c >> 1] = 1.0f; else p1[c >> 1] = 1.0f;
    (void)step_cascade(0.0f, CO, p1, p2);
    float m = (r & 1) ? p2[r >> 1] : p1[r >> 1];  // A element (r,c)
    for (int it = 0; it < LOG2L + LOG2P - 1; ++it) {
      float acc = 0.0f;
#pragma unroll
      for (int k = 0; k < NSTATE; ++k)
        acc = fmaf(__shfl(m, r * 8 + k), __shfl(m, k * 8 + c), acc);
      m = acc;
      if (it >= LOG2L - 1) Ms[it - (LOG2L - 1)][t] = m;
    }
  }

  float* __restrict__ vp = vbuf + ((size_t)blockIdx.x * P + t) * NSTATE;

  float w[NSTATE];
  {
    const float4 va = *reinterpret_cast<const float4*>(vp);
    const float4 vb = *reinterpret_cast<const float4*>(vp + 4);
    w[0] = va.x; w[1] = va.y; w[2] = va.z; w[3] = va.w;
    w[4] = vb.x; w[5] = vb.y; w[6] = vb.z; w[7] = vb.w;
  }
  __syncthreads();  // Ms ready

  for (int d = 0; d < LOG2P; ++d) {
#pragma unroll
    for (int r = 0; r < NSTATE; ++r) W[t][r] = w[r];
    __syncthreads();
    if (t >= (1 << d)) {
      const int src = t - (1 << d);
      float prev[NSTATE];
#pragma unroll
      for (int r = 0; r < NSTATE; ++r) prev[r] = W[src][r];
#pragma unroll
      for (int r = 0; r < NSTATE; ++r) {
        float acc = w[r];
#pragma unroll
        for (int k = 0; k < NSTATE; ++k)
          acc = fmaf(Ms[d][r * 8 + k], prev[k], acc);  // uniform addr: broadcast
        w[r] = acc;
      }
    }
    __syncthreads();
  }

  // exclusive shift: s_init(i) = (i==0 ? 0 : w_{i-1})
#pragma unroll
  for (int r = 0; r < NSTATE; ++r) W[t][r] = w[r];
  __syncthreads();
  float s[NSTATE];
  if (t == 0) {
#pragma unroll
    for (int r = 0; r < NSTATE; ++r) s[r] = 0.0f;
  } else {
#pragma unroll
    for (int r = 0; r < NSTATE; ++r) s[r] = W[t - 1][r];
  }
  *reinterpret_cast<float4*>(vp)     = make_float4(s[0], s[1], s[2], s[3]);
  *reinterpret_cast<float4*>(vp + 4) = make_float4(s[4], s[5], s[6], s[7]);
}

// ---------------------------------------------------------------------------
// Phase 3: replay from exact init. Stage in, compute in-place (own slots),
// barrier, linear coalesced stage-out.
__global__ __launch_bounds__(NT) void k_chunk_out(const float* __restrict__ x,
                                                  const float* __restrict__ bc,
                                                  const float* __restrict__ ac,
                                                  const float* __restrict__ sbuf_g,
                                                  float* __restrict__ out) {
  __shared__ float4 sbuf[NT * LQ];  // 16 KiB

  const int t = threadIdx.x;
  float b0[NS], b1[NS], b2[NS], a1[NS], a2[NS];
  load_coefs(bc, ac, b0, b1, b2, a1, a2);

  const float* __restrict__ sp =
      sbuf_g + ((size_t)blockIdx.x * NT + t) * NSTATE;
  const float4 sa = *reinterpret_cast<const float4*>(sp);
  const float4 sb = *reinterpret_cast<const float4*>(sp + 4);
  float s1[NS] = {sa.x, sa.z, sb.x, sb.z};
  float s2[NS] = {sa.y, sa.w, sb.y, sb.w};

  const float4* __restrict__ gsrc =
      reinterpret_cast<const float4*>(x) + (size_t)blockIdx.x * NT * LQ;
  float4* __restrict__ gdst =
      reinterpret_cast<float4*>(out) + (size_t)blockIdx.x * NT * LQ;

  stage_in(gsrc, sbuf, t);
  __syncthreads();

#pragma unroll
  for (int q = 0; q < LQ; ++q) {
    const int s = slot_of(t, q);
    sbuf[s] = out4(sbuf[s], CO, s1, s2);  // in-place: own slots only
  }
  __syncthreads();

#pragma unroll
  for (int k = 0; k < 16; ++k) {
    const int m = k * NT + t;
    gdst[m] = sbuf[slot_of(m >> 4, m & 15)];
  }
}

// ---------------------------------------------------------------------------
// Fallback (ws too small): one thread per batch, fully sequential but correct.
__global__ void k_naive(const float* __restrict__ x, const float* __restrict__ bc,
                        const float* __restrict__ ac, float* __restrict__ out) {
  const int bi = blockIdx.x * blockDim.x + threadIdx.x;
  if (bi >= BATCH) return;
  float b0[NS], b1[NS], b2[NS], a1[NS], a2[NS];
  load_coefs(bc, ac, b0, b1, b2, a1, a2);
  float s1[NS] = {0.f, 0.f, 0.f, 0.f};
  float s2[NS] = {0.f, 0.f, 0.f, 0.f};
  const float* __restrict__ xp = x + (size_t)bi * TLEN;
  float* __restrict__ op       = out + (size_t)bi * TLEN;
  for (int t = 0; t < TLEN; t += 4) {
    const float4 xv = *reinterpret_cast<const float4*>(xp + t);
    float4 y = out4(xv, CO, s1, s2);
    *reinterpret_cast<float4*>(op + t) = y;
  }
}

extern "C" void kernel_launch(void* const* d_in, const int* in_sizes, int n_in,
                              void* d_out, int out_size, void* d_ws, size_t ws_size,
                              hipStream_t stream) {
  const float* x  = (const float*)d_in[0];  // (B, T, 1)
  const float* bc = (const float*)d_in[1];  // (NS, 3)
  const float* ac = (const float*)d_in[2];  // (NS, 2)
  float* out = (float*)d_out;               // (B, T, 1)

  const size_t need = (size_t)BATCH * P * NSTATE * sizeof(float);
  if (ws_size < need) {
    k_naive<<<(BATCH + 255) / 256, 256, 0, stream>>>(x, bc, ac, out);
    return;
  }
  float* vbuf = (float*)d_ws;  // BATCH*P*8 floats

  k_chunk_state<<<(BATCH * P) / NT, NT, 0, stream>>>(x, bc, ac, vbuf);
  k_scan_par<<<BATCH, P, 0, stream>>>(bc, ac, vbuf);
  k_chunk_out<<<(BATCH * P) / NT, NT, 0, stream>>>(x, bc, ac, vbuf, out);
}

// Round 9
// 53.398 us; speedup vs baseline: 1.1743x; 1.1743x over previous
//
#include <hip/hip_runtime.h>

// Cascaded biquad IIR (DF2T) via linear state-space chunking. 2 main kernels:
//   1) k_state_scan: per-chunk final state (direct strided reads, no LDS)
//                    + in-block Kogge-Stone affine scan (block = one batch)
//   2) k_chunk_out:  replay each chunk from its exact initial state;
//                    direct strided reads; per-WAVE 8KB LDS write-transpose
//                    with wave-local s_waitcnt sync (no __syncthreads).

namespace {
constexpr int NS     = 4;
constexpr int BATCH  = 512;
constexpr int TLEN   = 32768;      // 2^15
constexpr int NSTATE = 8;
constexpr int P      = 512;        // chunks per batch
constexpr int L      = TLEN / P;   // 64 steps
constexpr int LQ     = L / 4;      // 16 float4 per chunk
constexpr int LOG2P  = 9;
constexpr int LOG2L  = 6;
}

__device__ __forceinline__ void load_coefs(const float* __restrict__ bc,
                                           const float* __restrict__ ac,
                                           float b0[NS], float b1[NS], float b2[NS],
                                           float a1[NS], float a2[NS]) {
#pragma unroll
  for (int k = 0; k < NS; ++k) {
    b0[k] = bc[3 * k];
    b1[k] = bc[3 * k + 1];
    b2[k] = bc[3 * k + 2];
    a1[k] = ac[2 * k];
    a2[k] = ac[2 * k + 1];
  }
}

// One time-step through the 4-section cascade (matches reference exactly).
__device__ __forceinline__ float step_cascade(float sig,
                                              const float b0[NS], const float b1[NS],
                                              const float b2[NS], const float a1[NS],
                                              const float a2[NS],
                                              float s1[NS], float s2[NS]) {
#pragma unroll
  for (int k = 0; k < NS; ++k) {
    float y = fmaf(b0[k], sig, s1[k]);
    s1[k]   = fmaf(-a1[k], y, fmaf(b1[k], sig, s2[k]));
    s2[k]   = fmaf(-a2[k], y, b2[k] * sig);
    sig = y;
  }
  return sig;
}

#define CO b0, b1, b2, a1, a2

__device__ __forceinline__ void adv4(const float4 u,
                                     const float b0[NS], const float b1[NS],
                                     const float b2[NS], const float a1[NS],
                                     const float a2[NS], float s1[NS], float s2[NS]) {
  (void)step_cascade(u.x, CO, s1, s2);
  (void)step_cascade(u.y, CO, s1, s2);
  (void)step_cascade(u.z, CO, s1, s2);
  (void)step_cascade(u.w, CO, s1, s2);
}

__device__ __forceinline__ float4 out4(const float4 u,
                                       const float b0[NS], const float b1[NS],
                                       const float b2[NS], const float a1[NS],
                                       const float a2[NS], float s1[NS], float s2[NS]) {
  float4 y;
  y.x = step_cascade(u.x, CO, s1, s2);
  y.y = step_cascade(u.y, CO, s1, s2);
  y.z = step_cascade(u.z, CO, s1, s2);
  y.w = step_cascade(u.w, CO, s1, s2);
  return y;
}

// ---------------------------------------------------------------------------
// Kernel 1: block = one batch (512 threads = 512 chunks). Each thread runs
// its chunk from zero state via direct strided reads (4-deep rolling
// prefetch, no LDS), then the block does the Kogge-Stone affine scan and
// writes s_init for every chunk.
__global__ __launch_bounds__(512) void k_state_scan(const float* __restrict__ x,
                                                    const float* __restrict__ bc,
                                                    const float* __restrict__ ac,
                                                    float* __restrict__ vbuf) {
  __shared__ float Ms[LOG2P][64];
  __shared__ float W[P][NSTATE + 1];  // stride 9: 2-way alias (free)

  const int t = threadIdx.x;
  float b0[NS], b1[NS], b2[NS], a1[NS], a2[NS];
  load_coefs(bc, ac, b0, b1, b2, a1, a2);

  // Wave 0: build Ms[d] = (A^L)^(2^d) in-register via __shfl.
  if (t < 64) {
    const int r = t >> 3, c = t & 7;
    float p1[NS] = {0.f, 0.f, 0.f, 0.f};
    float p2[NS] = {0.f, 0.f, 0.f, 0.f};
    if (c & 1) p2[c >> 1] = 1.0f; else p1[c >> 1] = 1.0f;
    (void)step_cascade(0.0f, CO, p1, p2);
    float m = (r & 1) ? p2[r >> 1] : p1[r >> 1];  // A element (r,c)
    for (int it = 0; it < LOG2L + LOG2P - 1; ++it) {
      float acc = 0.0f;
#pragma unroll
      for (int k = 0; k < NSTATE; ++k)
        acc = fmaf(__shfl(m, r * 8 + k), __shfl(m, k * 8 + c), acc);
      m = acc;
      if (it >= LOG2L - 1) Ms[it - (LOG2L - 1)][t] = m;
    }
  }

  // Chunk pass: direct strided reads, rolling 4-deep prefetch.
  const float4* __restrict__ gp =
      reinterpret_cast<const float4*>(x) + ((size_t)blockIdx.x * P + t) * LQ;
  float s1[NS] = {0.f, 0.f, 0.f, 0.f};
  float s2[NS] = {0.f, 0.f, 0.f, 0.f};
  float4 ld[4];
#pragma unroll
  for (int j = 0; j < 4; ++j) ld[j] = gp[j];
#pragma unroll
  for (int q0 = 0; q0 < LQ; q0 += 4) {
#pragma unroll
    for (int j = 0; j < 4; ++j) {
      const float4 u = ld[j];
      if (q0 + 4 + j < LQ) ld[j] = gp[q0 + 4 + j];
      adv4(u, CO, s1, s2);
    }
  }

  float w[NSTATE];
#pragma unroll
  for (int k = 0; k < NS; ++k) { w[2 * k] = s1[k]; w[2 * k + 1] = s2[k]; }

  // Kogge-Stone: w_i <- Ms[d]*w_{i-2^d} + w_i
  for (int d = 0; d < LOG2P; ++d) {
#pragma unroll
    for (int r = 0; r < NSTATE; ++r) W[t][r] = w[r];
    __syncthreads();  // also orders wave0's Ms writes before first use
    if (t >= (1 << d)) {
      const int src = t - (1 << d);
      float prev[NSTATE];
#pragma unroll
      for (int r = 0; r < NSTATE; ++r) prev[r] = W[src][r];
#pragma unroll
      for (int r = 0; r < NSTATE; ++r) {
        float acc = w[r];
#pragma unroll
        for (int k = 0; k < NSTATE; ++k)
          acc = fmaf(Ms[d][r * 8 + k], prev[k], acc);  // uniform addr: broadcast
        w[r] = acc;
      }
    }
    __syncthreads();
  }

  // exclusive shift: s_init(i) = (i==0 ? 0 : w_{i-1})
#pragma unroll
  for (int r = 0; r < NSTATE; ++r) W[t][r] = w[r];
  __syncthreads();
  float s[NSTATE];
  if (t == 0) {
#pragma unroll
    for (int r = 0; r < NSTATE; ++r) s[r] = 0.0f;
  } else {
#pragma unroll
    for (int r = 0; r < NSTATE; ++r) s[r] = W[t - 1][r];
  }
  float* __restrict__ vp = vbuf + ((size_t)blockIdx.x * P + t) * NSTATE;
  *reinterpret_cast<float4*>(vp)     = make_float4(s[0], s[1], s[2], s[3]);
  *reinterpret_cast<float4*>(vp + 4) = make_float4(s[4], s[5], s[6], s[7]);
}

// ---------------------------------------------------------------------------
// Kernel 2: replay from exact init. 256 threads = 4 INDEPENDENT waves, each
// owning 64 chunks + its own 8KB LDS region. Reads are direct strided with
// rolling prefetch; outputs are transposed through LDS in two 8-f4 tiles;
// sync is wave-local s_waitcnt (no __syncthreads, no block lockstep).
__global__ __launch_bounds__(256) void k_chunk_out(const float* __restrict__ x,
                                                   const float* __restrict__ bc,
                                                   const float* __restrict__ ac,
                                                   const float* __restrict__ sbuf_g,
                                                   float* __restrict__ out) {
  __shared__ float4 lds[4][512];  // 8KB per wave, 32KB total

  const int tt = threadIdx.x;
  const int t  = tt & 63;         // lane
  const int w  = tt >> 6;         // wave
  const size_t cg = (size_t)blockIdx.x * 256 + tt;  // global chunk

  float b0[NS], b1[NS], b2[NS], a1[NS], a2[NS];
  load_coefs(bc, ac, b0, b1, b2, a1, a2);

  const float* __restrict__ sp = sbuf_g + cg * NSTATE;
  const float4 sa = *reinterpret_cast<const float4*>(sp);
  const float4 sb = *reinterpret_cast<const float4*>(sp + 4);
  float s1[NS] = {sa.x, sa.z, sb.x, sb.z};
  float s2[NS] = {sa.y, sa.w, sb.y, sb.w};

  const float4* __restrict__ gp  = reinterpret_cast<const float4*>(x) + cg * LQ;
  float4* __restrict__ gout =
      reinterpret_cast<float4*>(out) + ((size_t)blockIdx.x * 256 + (w << 6)) * LQ;
  float4* __restrict__ Lb = lds[w];

  float4 ld[4];
#pragma unroll
  for (int j = 0; j < 4; ++j) ld[j] = gp[j];

  // ---- tile 0: steps 0..31 (f4 0..7), write y to swizzled LDS slots
#pragma unroll
  for (int q = 0; q < 8; ++q) {
    const float4 u = ld[q & 3];
    ld[q & 3] = gp[q + 4];  // q+4 <= 11 < LQ always here
    Lb[t * 8 + (q ^ (t & 7))] = out4(u, CO, s1, s2);
  }
  asm volatile("s_waitcnt lgkmcnt(0)" ::: "memory");
  __builtin_amdgcn_sched_barrier(0);
  // coalesced store: 8 lanes cover one full 128B line per chunk
#pragma unroll
  for (int k = 0; k < 8; ++k) {
    const int s = k * 64 + t;
    const int c = s >> 3, q = s & 7;
    gout[c * 16 + q] = Lb[c * 8 + (q ^ (c & 7))];
  }
  asm volatile("s_waitcnt lgkmcnt(0)" ::: "memory");  // WAR: reads done before reuse
  __builtin_amdgcn_sched_barrier(0);

  // ---- tile 1: steps 32..63 (f4 8..15)
#pragma unroll
  for (int q = 8; q < 16; ++q) {
    const float4 u = ld[q & 3];
    if (q + 4 < 16) ld[q & 3] = gp[q + 4];
    Lb[t * 8 + ((q & 7) ^ (t & 7))] = out4(u, CO, s1, s2);
  }
  asm volatile("s_waitcnt lgkmcnt(0)" ::: "memory");
  __builtin_amdgcn_sched_barrier(0);
#pragma unroll
  for (int k = 0; k < 8; ++k) {
    const int s = k * 64 + t;
    const int c = s >> 3, q = s & 7;
    gout[c * 16 + 8 + q] = Lb[c * 8 + (q ^ (c & 7))];
  }
}

// ---------------------------------------------------------------------------
// Fallback (ws too small): one thread per batch, fully sequential but correct.
__global__ void k_naive(const float* __restrict__ x, const float* __restrict__ bc,
                        const float* __restrict__ ac, float* __restrict__ out) {
  const int bi = blockIdx.x * blockDim.x + threadIdx.x;
  if (bi >= BATCH) return;
  float b0[NS], b1[NS], b2[NS], a1[NS], a2[NS];
  load_coefs(bc, ac, b0, b1, b2, a1, a2);
  float s1[NS] = {0.f, 0.f, 0.f, 0.f};
  float s2[NS] = {0.f, 0.f, 0.f, 0.f};
  const float* __restrict__ xp = x + (size_t)bi * TLEN;
  float* __restrict__ op       = out + (size_t)bi * TLEN;
  for (int t = 0; t < TLEN; t += 4) {
    const float4 xv = *reinterpret_cast<const float4*>(xp + t);
    float4 y = out4(xv, CO, s1, s2);
    *reinterpret_cast<float4*>(op + t) = y;
  }
}

extern "C" void kernel_launch(void* const* d_in, const int* in_sizes, int n_in,
                              void* d_out, int out_size, void* d_ws, size_t ws_size,
                              hipStream_t stream) {
  const float* x  = (const float*)d_in[0];  // (B, T, 1)
  const float* bc = (const float*)d_in[1];  // (NS, 3)
  const float* ac = (const float*)d_in[2];  // (NS, 2)
  float* out = (float*)d_out;               // (B, T, 1)

  const size_t need = (size_t)BATCH * P * NSTATE * sizeof(float);
  if (ws_size < need) {
    k_naive<<<(BATCH + 255) / 256, 256, 0, stream>>>(x, bc, ac, out);
    return;
  }
  float* vbuf = (float*)d_ws;  // BATCH*P*8 floats: s_init per chunk

  k_state_scan<<<BATCH, P, 0, stream>>>(x, bc, ac, vbuf);
  k_chunk_out<<<(BATCH * P) / 256, 256, 0, stream>>>(x, bc, ac, vbuf, out);
}

// Round 10
// 42.222 us; speedup vs baseline: 1.4851x; 1.2647x over previous
//
#include <hip/hip_runtime.h>

// Fully-fused cascaded-biquad IIR (DF2T) via linear state-space chunking.
// ONE kernel, block = one batch row (512 blocks x 512 threads):
//   1) per-chunk final state from zero init (direct strided reads, 4-deep
//      rolling prefetch, no LDS)
//   2) in-block Kogge-Stone affine scan (wave 0 pre-builds (A^64)^(2^d)
//      in-register via __shfl)
//   3) exclusive shift -> each thread's exact s_init stays IN REGISTERS
//   4) replay: re-read x (L3-resident), per-WAVE 8KB LDS write-transpose,
//      wave-local s_waitcnt sync, 128B-dense coalesced stores.
// LDS: one 64KB arena; scan buffers (Ms+W, 20.7KB) and the 8 per-wave
// replay regions alias it (separated by a barrier). No workspace.

namespace {
constexpr int NS     = 4;
constexpr int BATCH  = 512;
constexpr int TLEN   = 32768;      // 2^15
constexpr int NSTATE = 8;
constexpr int P      = 512;        // chunks per batch = threads per block
constexpr int L      = TLEN / P;   // 64 steps per chunk
constexpr int LQ     = L / 4;      // 16 float4 per chunk
constexpr int LOG2P  = 9;
constexpr int LOG2L  = 6;
}

__device__ __forceinline__ void load_coefs(const float* __restrict__ bc,
                                           const float* __restrict__ ac,
                                           float b0[NS], float b1[NS], float b2[NS],
                                           float a1[NS], float a2[NS]) {
#pragma unroll
  for (int k = 0; k < NS; ++k) {
    b0[k] = bc[3 * k];
    b1[k] = bc[3 * k + 1];
    b2[k] = bc[3 * k + 2];
    a1[k] = ac[2 * k];
    a2[k] = ac[2 * k + 1];
  }
}

// One time-step through the 4-section cascade (matches reference exactly).
__device__ __forceinline__ float step_cascade(float sig,
                                              const float b0[NS], const float b1[NS],
                                              const float b2[NS], const float a1[NS],
                                              const float a2[NS],
                                              float s1[NS], float s2[NS]) {
#pragma unroll
  for (int k = 0; k < NS; ++k) {
    float y = fmaf(b0[k], sig, s1[k]);
    s1[k]   = fmaf(-a1[k], y, fmaf(b1[k], sig, s2[k]));
    s2[k]   = fmaf(-a2[k], y, b2[k] * sig);
    sig = y;
  }
  return sig;
}

#define CO b0, b1, b2, a1, a2

__device__ __forceinline__ void adv4(const float4 u,
                                     const float b0[NS], const float b1[NS],
                                     const float b2[NS], const float a1[NS],
                                     const float a2[NS], float s1[NS], float s2[NS]) {
  (void)step_cascade(u.x, CO, s1, s2);
  (void)step_cascade(u.y, CO, s1, s2);
  (void)step_cascade(u.z, CO, s1, s2);
  (void)step_cascade(u.w, CO, s1, s2);
}

__device__ __forceinline__ float4 out4(const float4 u,
                                       const float b0[NS], const float b1[NS],
                                       const float b2[NS], const float a1[NS],
                                       const float a2[NS], float s1[NS], float s2[NS]) {
  float4 y;
  y.x = step_cascade(u.x, CO, s1, s2);
  y.y = step_cascade(u.y, CO, s1, s2);
  y.z = step_cascade(u.z, CO, s1, s2);
  y.w = step_cascade(u.w, CO, s1, s2);
  return y;
}

__global__ __launch_bounds__(P) void k_fused(const float* __restrict__ x,
                                             const float* __restrict__ bc,
                                             const float* __restrict__ ac,
                                             float* __restrict__ out) {
  // 64 KiB arena. Scan phase: Ms = arena[0..575] floats, W = floats 576..5183
  // (stride 9). Replay phase: wave w owns float4s [w*512, w*512+512).
  __shared__ float4 arena[4096];
  float* Msf = reinterpret_cast<float*>(arena);        // [LOG2P][64]
  float* Wf  = reinterpret_cast<float*>(arena) + 576;  // [P][9]

  const int t = threadIdx.x;
  float b0[NS], b1[NS], b2[NS], a1[NS], a2[NS];
  load_coefs(bc, ac, b0, b1, b2, a1, a2);

  // ---- wave 0: Ms[d] = (A^L)^(2^d) in-register via __shfl ----
  if (t < 64) {
    const int r = t >> 3, c = t & 7;
    float p1[NS] = {0.f, 0.f, 0.f, 0.f};
    float p2[NS] = {0.f, 0.f, 0.f, 0.f};
    if (c & 1) p2[c >> 1] = 1.0f; else p1[c >> 1] = 1.0f;
    (void)step_cascade(0.0f, CO, p1, p2);
    float m = (r & 1) ? p2[r >> 1] : p1[r >> 1];  // A element (r,c)
    for (int it = 0; it < LOG2L + LOG2P - 1; ++it) {
      float acc = 0.0f;
#pragma unroll
      for (int k = 0; k < NSTATE; ++k)
        acc = fmaf(__shfl(m, r * 8 + k), __shfl(m, k * 8 + c), acc);
      m = acc;
      if (it >= LOG2L - 1) Msf[(it - (LOG2L - 1)) * 64 + t] = m;
    }
  }

  // ---- phase 1: chunk final state from zero (direct strided reads) ----
  const float4* __restrict__ gp =
      reinterpret_cast<const float4*>(x) + ((size_t)blockIdx.x * P + t) * LQ;
  float s1[NS] = {0.f, 0.f, 0.f, 0.f};
  float s2[NS] = {0.f, 0.f, 0.f, 0.f};
  float4 ld[4];
#pragma unroll
  for (int j = 0; j < 4; ++j) ld[j] = gp[j];
#pragma unroll
  for (int q0 = 0; q0 < LQ; q0 += 4) {
#pragma unroll
    for (int j = 0; j < 4; ++j) {
      const float4 u = ld[j];
      if (q0 + 4 + j < LQ) ld[j] = gp[q0 + 4 + j];
      adv4(u, CO, s1, s2);
    }
  }

  float w[NSTATE];
#pragma unroll
  for (int k = 0; k < NS; ++k) { w[2 * k] = s1[k]; w[2 * k + 1] = s2[k]; }

  // ---- phase 2: Kogge-Stone affine scan ----
  for (int d = 0; d < LOG2P; ++d) {
#pragma unroll
    for (int r = 0; r < NSTATE; ++r) Wf[t * 9 + r] = w[r];
    __syncthreads();  // also orders wave0's Ms writes before first use
    if (t >= (1 << d)) {
      const int src = (t - (1 << d)) * 9;
      float prev[NSTATE];
#pragma unroll
      for (int r = 0; r < NSTATE; ++r) prev[r] = Wf[src + r];
#pragma unroll
      for (int r = 0; r < NSTATE; ++r) {
        float acc = w[r];
#pragma unroll
        for (int k = 0; k < NSTATE; ++k)
          acc = fmaf(Msf[d * 64 + r * 8 + k], prev[k], acc);  // uniform: broadcast
        w[r] = acc;
      }
    }
    __syncthreads();
  }

  // ---- phase 3: exclusive shift -> s_init in registers ----
#pragma unroll
  for (int r = 0; r < NSTATE; ++r) Wf[t * 9 + r] = w[r];
  __syncthreads();
  {
    const int src = (t == 0 ? 0 : t - 1) * 9;
#pragma unroll
    for (int k = 0; k < NS; ++k) {
      s1[k] = (t == 0) ? 0.0f : Wf[src + 2 * k];
      s2[k] = (t == 0) ? 0.0f : Wf[src + 2 * k + 1];
    }
  }
  __syncthreads();  // all scan reads done before replay overwrites the arena

  // ---- phase 4: replay from exact init; per-wave LDS transpose out ----
  const int lane = t & 63;
  const int wv   = t >> 6;
  float4* __restrict__ Lb = arena + (wv << 9);  // 8KB per wave
  float4* __restrict__ gout = reinterpret_cast<float4*>(out) +
      ((size_t)blockIdx.x * P + (wv << 6)) * LQ;

#pragma unroll
  for (int j = 0; j < 4; ++j) ld[j] = gp[j];

  // tile 0: steps 0..31 (f4 0..7) -> swizzled LDS -> coalesced store
#pragma unroll
  for (int q = 0; q < 8; ++q) {
    const float4 u = ld[q & 3];
    ld[q & 3] = gp[q + 4];  // q+4 <= 11 < LQ
    Lb[lane * 8 + (q ^ (lane & 7))] = out4(u, CO, s1, s2);
  }
  asm volatile("s_waitcnt lgkmcnt(0)" ::: "memory");
  __builtin_amdgcn_sched_barrier(0);
#pragma unroll
  for (int k = 0; k < 8; ++k) {
    const int s = k * 64 + lane;
    const int c = s >> 3, q = s & 7;
    gout[c * 16 + q] = Lb[c * 8 + (q ^ (c & 7))];
  }
  asm volatile("s_waitcnt lgkmcnt(0)" ::: "memory");  // WAR before region reuse
  __builtin_amdgcn_sched_barrier(0);

  // tile 1: steps 32..63 (f4 8..15)
#pragma unroll
  for (int q = 8; q < 16; ++q) {
    const float4 u = ld[q & 3];
    if (q + 4 < 16) ld[q & 3] = gp[q + 4];
    Lb[lane * 8 + ((q & 7) ^ (lane & 7))] = out4(u, CO, s1, s2);
  }
  asm volatile("s_waitcnt lgkmcnt(0)" ::: "memory");
  __builtin_amdgcn_sched_barrier(0);
#pragma unroll
  for (int k = 0; k < 8; ++k) {
    const int s = k * 64 + lane;
    const int c = s >> 3, q = s & 7;
    gout[c * 16 + 8 + q] = Lb[c * 8 + (q ^ (c & 7))];
  }
}

extern "C" void kernel_launch(void* const* d_in, const int* in_sizes, int n_in,
                              void* d_out, int out_size, void* d_ws, size_t ws_size,
                              hipStream_t stream) {
  const float* x  = (const float*)d_in[0];  // (B, T, 1)
  const float* bc = (const float*)d_in[1];  // (NS, 3)
  const float* ac = (const float*)d_in[2];  // (NS, 2)
  float* out = (float*)d_out;               // (B, T, 1)

  k_fused<<<BATCH, P, 0, stream>>>(x, bc, ac, out);
}